// Round 1
// baseline (1387.717 us; speedup 1.0000x reference)
//
#include <hip/hip_runtime.h>

#define DI __device__ __forceinline__

DI float silu_f(float x){ return x * (1.0f / (1.0f + __expf(-x))); }

// ---------------------------------------------------------------------------
// Generic direct conv, NHWC input, HWIO weights.
// Thread = (pixel-group of NPIX flattened output pixels, one co).
// co fastest across lanes -> weight loads coalesced; input loads wave-uniform.
// ---------------------------------------------------------------------------
template<int KH,int KW,int STRIDE,int PAD,int CIN,int COUT,bool ACT,int NPIX>
__global__ __launch_bounds__(256) void conv2d_k(
    const float* __restrict__ in, const float* __restrict__ w,
    const float* __restrict__ bias, float* __restrict__ out,
    int N,int H,int W,int OH,int OW)
{
  int idx = blockIdx.x*256 + threadIdx.x;
  int co  = idx % COUT;
  int pg  = idx / COUT;
  int p0  = pg * NPIX;
  int total = N*OH*OW;
  if (p0 >= total) return;

  float acc[NPIX];
#pragma unroll
  for (int t=0;t<NPIX;t++) acc[t]=0.f;

  int iy0[NPIX], ix0[NPIX];
  const float* base[NPIX];
  bool pv[NPIX];
#pragma unroll
  for (int t=0;t<NPIX;t++){
    int p = p0+t;
    pv[t] = (p<total);
    int pp = pv[t]?p:p0;
    int ox = pp % OW; int r = pp/OW;
    int oy = r % OH;  int n = r/OH;
    iy0[t]=oy*STRIDE-PAD; ix0[t]=ox*STRIDE-PAD;
    base[t]= in + (size_t)n*H*W*CIN;
  }

  for (int ky=0; ky<KH; ky++){
    for (int kx=0; kx<KW; kx++){
      const float* wp = w + (size_t)((ky*KW+kx)*CIN)*COUT + co;
      const float* ip[NPIX]; bool ok[NPIX];
#pragma unroll
      for (int t=0;t<NPIX;t++){
        int iy=iy0[t]+ky, ix=ix0[t]+kx;
        ok[t] = pv[t] && iy>=0 && iy<H && ix>=0 && ix<W;
        ip[t] = base[t] + (size_t)(iy*W+ix)*CIN;
      }
      if constexpr ((CIN & 3) == 0) {
#pragma unroll 2
        for (int ci=0; ci<CIN; ci+=4){
          float w0=wp[(ci+0)*COUT], w1=wp[(ci+1)*COUT];
          float w2=wp[(ci+2)*COUT], w3=wp[(ci+3)*COUT];
#pragma unroll
          for (int t=0;t<NPIX;t++){
            float4 v = ok[t] ? *reinterpret_cast<const float4*>(ip[t]+ci)
                             : make_float4(0.f,0.f,0.f,0.f);
            acc[t]=fmaf(w0,v.x,acc[t]); acc[t]=fmaf(w1,v.y,acc[t]);
            acc[t]=fmaf(w2,v.z,acc[t]); acc[t]=fmaf(w3,v.w,acc[t]);
          }
        }
      } else {
#pragma unroll
        for (int ci=0; ci<CIN; ci++){
          float wv = wp[ci*COUT];
#pragma unroll
          for (int t=0;t<NPIX;t++){
            float v = ok[t] ? ip[t][ci] : 0.f;
            acc[t]=fmaf(wv,v,acc[t]);
          }
        }
      }
    }
  }
  float b = bias[co];
#pragma unroll
  for (int t=0;t<NPIX;t++){
    if (pv[t]){
      float v = acc[t]+b;
      if (ACT) v = silu_f(v);
      out[(size_t)(p0+t)*COUT + co] = v;
    }
  }
}

// ---------------------------------------------------------------------------
// conv_transpose 5x5 stride 2, SAME (JAX: lhs_dilation=2, pad_a=3, pad_b=2,
// kernel NOT flipped, HWIO as-is). One kernel per output parity (PY,PX):
// even rows use ky in {1,3}, odd rows ky in {0,2,4}; iy = yy + j - 1.
// ---------------------------------------------------------------------------
template<int CIN,int COUT,bool ACT,int PY,int PX,int NPIX>
__global__ __launch_bounds__(256) void tconv_k(
    const float* __restrict__ in, const float* __restrict__ w,
    const float* __restrict__ bias, float* __restrict__ out,
    int N,int H,int W,int OH,int OW)
{
  constexpr int NKY = PY?3:2, NKX = PX?3:2;
  int idx = blockIdx.x*256 + threadIdx.x;
  int co = idx % COUT;
  int pg = idx / COUT;
  int p0 = pg*NPIX;
  int OHh=OH>>1, OWh=OW>>1;
  int total = N*OHh*OWh;
  if (p0>=total) return;

  float acc[NPIX];
#pragma unroll
  for (int t=0;t<NPIX;t++) acc[t]=0.f;
  int yy[NPIX], xx[NPIX], nn[NPIX]; bool pv[NPIX];
#pragma unroll
  for (int t=0;t<NPIX;t++){
    int p=p0+t; pv[t]=(p<total); int pp=pv[t]?p:p0;
    xx[t]=pp%OWh; int r=pp/OWh; yy[t]=r%OHh; nn[t]=r/OHh;
  }

#pragma unroll
  for (int j=0;j<NKY;j++){
    int ky = 2*j + (PY?0:1);
#pragma unroll
    for (int i=0;i<NKX;i++){
      int kx = 2*i + (PX?0:1);
      const float* wp = w + (size_t)((ky*5+kx)*CIN)*COUT + co;
      const float* ip[NPIX]; bool ok[NPIX];
#pragma unroll
      for (int t=0;t<NPIX;t++){
        int iy=yy[t]+j-1, ix=xx[t]+i-1;
        ok[t]=pv[t] && iy>=0 && iy<H && ix>=0 && ix<W;
        ip[t]= in + (((size_t)nn[t]*H + iy)*W + ix)*CIN;
      }
#pragma unroll 2
      for (int ci=0;ci<CIN;ci+=4){
        float w0=wp[(ci+0)*COUT],w1=wp[(ci+1)*COUT];
        float w2=wp[(ci+2)*COUT],w3=wp[(ci+3)*COUT];
#pragma unroll
        for (int t=0;t<NPIX;t++){
          float4 v = ok[t]?*reinterpret_cast<const float4*>(ip[t]+ci)
                          :make_float4(0.f,0.f,0.f,0.f);
          acc[t]=fmaf(w0,v.x,acc[t]); acc[t]=fmaf(w1,v.y,acc[t]);
          acc[t]=fmaf(w2,v.z,acc[t]); acc[t]=fmaf(w3,v.w,acc[t]);
        }
      }
    }
  }
  float b=bias[co];
#pragma unroll
  for (int t=0;t<NPIX;t++) if(pv[t]){
    float v=acc[t]+b; if(ACT)v=silu_f(v);
    out[(((size_t)nn[t]*OH + (2*yy[t]+PY))*OW + (2*xx[t]+PX))*COUT + co]=v;
  }
}

// ---------------------------------------------------------------------------
// VQ: one wave per latent vector (dim 128). Latent staged in LDS; each lane
// evaluates 4 codes (lane, lane+64, lane+128, lane+192) with the reference
// formula sum((lat-c)^2); shuffle-argmin with lowest-index tie-break.
// ---------------------------------------------------------------------------
__global__ __launch_bounds__(256) void vq_k(
    const float* __restrict__ lat, const float* __restrict__ cb,
    float* __restrict__ q, int NLat)
{
  __shared__ float slat[4][128];
  int wave = threadIdx.x >> 6;
  int lane = threadIdx.x & 63;
  int l = blockIdx.x*4 + wave;
  if (l >= NLat) return;
  const float* lp = lat + (size_t)l*128;
  slat[wave][lane]    = lp[lane];
  slat[wave][lane+64] = lp[lane+64];

  float bestd = INFINITY; int besti = 0;
  for (int c0=0;c0<256;c0+=64){
    int c = c0 + lane;
    const float* cp = cb + (size_t)c*128;
    float d = 0.f;
#pragma unroll 8
    for (int k=0;k<128;k+=4){
      float4 cv = *reinterpret_cast<const float4*>(cp+k);
      float d0 = slat[wave][k+0]-cv.x;
      float d1 = slat[wave][k+1]-cv.y;
      float d2 = slat[wave][k+2]-cv.z;
      float d3 = slat[wave][k+3]-cv.w;
      d += d0*d0; d += d1*d1; d += d2*d2; d += d3*d3;
    }
    if (d < bestd) { bestd = d; besti = c; }   // c ascending within lane
  }
  for (int off=32; off; off>>=1){
    float od = __shfl_down(bestd, off);
    int   oi = __shfl_down(besti, off);
    if (od < bestd || (od == bestd && oi < besti)) { bestd=od; besti=oi; }
  }
  besti = __shfl(besti, 0);
  const float* cp = cb + (size_t)besti*128;
  float* qp = q + (size_t)l*128;
  qp[lane]    = cp[lane];
  qp[lane+64] = cp[lane+64];
}

// ---------------------------------------------------------------------------
// Final 3x3 conv, 32 -> 3 channels. Thread = one output pixel (3 channels).
// ---------------------------------------------------------------------------
__global__ __launch_bounds__(256) void conv_last_k(
    const float* __restrict__ in, const float* __restrict__ w,
    const float* __restrict__ bias, float* __restrict__ out,
    int N,int H,int W)
{
  int p = blockIdx.x*256 + threadIdx.x;
  int total = N*H*W;
  if (p>=total) return;
  int x = p % W; int r = p / W; int y = r % H; int n = r / H;
  float a0=bias[0], a1=bias[1], a2=bias[2];
  const float* base = in + (size_t)n*H*W*32;
  for (int ky=0;ky<3;ky++){ int iy=y+ky-1; if(iy<0||iy>=H) continue;
    for (int kx=0;kx<3;kx++){ int ix=x+kx-1; if(ix<0||ix>=W) continue;
      const float* ip = base + (size_t)(iy*W+ix)*32;
      const float* wp = w + (size_t)((ky*3+kx)*32)*3;
#pragma unroll
      for (int ci=0;ci<32;ci++){
        float v = ip[ci];
        a0 = fmaf(v, wp[ci*3+0], a0);
        a1 = fmaf(v, wp[ci*3+1], a1);
        a2 = fmaf(v, wp[ci*3+2], a2);
      }
    }
  }
  out[(size_t)p*3+0]=a0; out[(size_t)p*3+1]=a1; out[(size_t)p*3+2]=a2;
}

extern "C" void kernel_launch(void* const* d_in, const int* in_sizes, int n_in,
                              void* d_out, int out_size, void* d_ws, size_t ws_size,
                              hipStream_t stream) {
  const float* x    = (const float*)d_in[0];
  const float* k1   = (const float*)d_in[1];  const float* b1  = (const float*)d_in[2];
  const float* k1c  = (const float*)d_in[3];  const float* b1c = (const float*)d_in[4];
  const float* k2   = (const float*)d_in[5];  const float* b2  = (const float*)d_in[6];
  const float* k2c  = (const float*)d_in[7];  const float* b2c = (const float*)d_in[8];
  const float* k3   = (const float*)d_in[9];  const float* b3  = (const float*)d_in[10];
  const float* k3c  = (const float*)d_in[11]; const float* b3c = (const float*)d_in[12];
  const float* cb   = (const float*)d_in[13];
  const float* tk1  = (const float*)d_in[14]; const float* tb1  = (const float*)d_in[15];
  const float* tk1c = (const float*)d_in[16]; const float* tb1c = (const float*)d_in[17];
  const float* tk2  = (const float*)d_in[18]; const float* tb2  = (const float*)d_in[19];
  const float* tk2c = (const float*)d_in[20]; const float* tb2c = (const float*)d_in[21];
  const float* tk3  = (const float*)d_in[22]; const float* tb3  = (const float*)d_in[23];
  const float* tk3c = (const float*)d_in[24]; const float* tb3c = (const float*)d_in[25];
  float* out = (float*)d_out;

  // ping-pong workspace: A = 4 MB region, B = 16 MB region (u3 lives in B)
  float* A = (float*)d_ws;                 // max 1,048,576 floats
  float* B = A + 1048576;                  // max 4,194,304 floats

  dim3 blk(256);
  // encoder
  conv2d_k<11,11,2,4,  3, 32,true ,4><<<1024, blk,0,stream>>>(x, k1, b1, A, 8,128,128,64,64);
  conv2d_k< 3, 3,1,1, 32, 32,true ,4><<<1024, blk,0,stream>>>(A, k1c,b1c,B, 8, 64, 64,64,64);
  conv2d_k<11,11,2,4, 32, 64,true ,4><<< 512, blk,0,stream>>>(B, k2, b2, A, 8, 64, 64,32,32);
  conv2d_k< 3, 3,1,1, 64, 64,true ,4><<< 512, blk,0,stream>>>(A, k2c,b2c,B, 8, 32, 32,32,32);
  conv2d_k<11,11,2,4, 64,128,true ,2><<< 512, blk,0,stream>>>(B, k3, b3, A, 8, 32, 32,16,16);
  conv2d_k< 3, 3,1,1,128,128,false,2><<< 512, blk,0,stream>>>(A, k3c,b3c,B, 8, 16, 16,16,16);
  // vector quantization: B (latents) -> A (quantized)
  vq_k<<<512, blk,0,stream>>>(B, cb, A, 2048);
  // decoder
  tconv_k<128,64,true,0,0,2><<<256, blk,0,stream>>>(A, tk1,tb1,B, 8,16,16,32,32);
  tconv_k<128,64,true,0,1,2><<<256, blk,0,stream>>>(A, tk1,tb1,B, 8,16,16,32,32);
  tconv_k<128,64,true,1,0,2><<<256, blk,0,stream>>>(A, tk1,tb1,B, 8,16,16,32,32);
  tconv_k<128,64,true,1,1,2><<<256, blk,0,stream>>>(A, tk1,tb1,B, 8,16,16,32,32);
  conv2d_k<3,3,1,1,64,64,true,4><<<512, blk,0,stream>>>(B, tk1c,tb1c,A, 8,32,32,32,32);
  tconv_k< 64,32,true,0,0,4><<<256, blk,0,stream>>>(A, tk2,tb2,B, 8,32,32,64,64);
  tconv_k< 64,32,true,0,1,4><<<256, blk,0,stream>>>(A, tk2,tb2,B, 8,32,32,64,64);
  tconv_k< 64,32,true,1,0,4><<<256, blk,0,stream>>>(A, tk2,tb2,B, 8,32,32,64,64);
  tconv_k< 64,32,true,1,1,4><<<256, blk,0,stream>>>(A, tk2,tb2,B, 8,32,32,64,64);
  conv2d_k<3,3,1,1,32,32,true,4><<<1024, blk,0,stream>>>(B, tk2c,tb2c,A, 8,64,64,64,64);
  tconv_k< 32,32,true,0,0,4><<<1024, blk,0,stream>>>(A, tk3,tb3,B, 8,64,64,128,128);
  tconv_k< 32,32,true,0,1,4><<<1024, blk,0,stream>>>(A, tk3,tb3,B, 8,64,64,128,128);
  tconv_k< 32,32,true,1,0,4><<<1024, blk,0,stream>>>(A, tk3,tb3,B, 8,64,64,128,128);
  tconv_k< 32,32,true,1,1,4><<<1024, blk,0,stream>>>(A, tk3,tb3,B, 8,64,64,128,128);
  conv_last_k<<<512, blk,0,stream>>>(B, tk3c, tb3c, out, 8,128,128);
}

// Round 2
// 1062.609 us; speedup vs baseline: 1.3060x; 1.3060x over previous
//
#include <hip/hip_runtime.h>

#define DI __device__ __forceinline__
DI float silu_f(float x){ return x * (1.0f/(1.0f+__expf(-x))); }

// ---------------------------------------------------------------------------
// Direct conv, NHWC input, HWIO weights. Thread = NPIX pixels x 4 co.
// Weight loads: float4 (co quad), coalesced across lanes. Input loads: float4
// over ci, broadcast across co-quads. G>1: ci-split into G groups (group in
// blockIdx.x low bits), each writes a full-size partial at out + g*N*OH*OW*CO.
// ---------------------------------------------------------------------------
template<int KH,int KW,int STRIDE,int PAD,int CIN,int COUT,int NPIX,bool ACT,bool BIAS,int G>
__global__ __launch_bounds__(256) void conv_k(
    const float* __restrict__ in, const float* __restrict__ w,
    const float* __restrict__ bias, float* __restrict__ out,
    int N,int H,int W,int OH,int OW)
{
  constexpr int COQ  = COUT/4;
  constexpr int CLEN = CIN/G;
  constexpr int GSH  = (G==4)?2:(G==2)?1:0;
  static_assert(G==1||G==2||G==4, "G");
  static_assert(CIN==3 || (CLEN%4)==0, "ci");

  const int g  = blockIdx.x & (G-1);
  const int bx = blockIdx.x >> GSH;
  const int total = N*OH*OW;
  out += (size_t)g * total * COUT;

  int idx = bx*256 + threadIdx.x;
  int cq = idx % COQ;
  int pg = idx / COQ;
  int co = cq*4;
  int p0 = pg*NPIX;
  if (p0 >= total) return;

  float acc[NPIX][4] = {};
  int iy0[NPIX], ix0[NPIX]; const float* base[NPIX]; bool pv[NPIX];
#pragma unroll
  for (int t=0;t<NPIX;t++){
    int p=p0+t; pv[t]=(p<total); int pp=pv[t]?p:p0;
    int ox=pp%OW; int r=pp/OW; int oy=r%OH; int n=r/OH;
    iy0[t]=oy*STRIDE-PAD; ix0[t]=ox*STRIDE-PAD;
    base[t]=in+(size_t)n*H*W*CIN + g*CLEN;
  }

  for (int ky=0; ky<KH; ky++){
    for (int kx=0; kx<KW; kx++){
      const float* wp = w + ((size_t)(ky*KW+kx)*CIN + g*CLEN)*COUT + co;
      const float* ip[NPIX]; bool ok[NPIX];
#pragma unroll
      for (int t=0;t<NPIX;t++){
        int iy=iy0[t]+ky, ix=ix0[t]+kx;
        ok[t]=pv[t] && iy>=0 && iy<H && ix>=0 && ix<W;
        ip[t]=base[t]+(size_t)(iy*W+ix)*CIN;
      }
      if constexpr (CIN==3){
        float wv[3][4];
        *(float4*)wv[0]=*(const float4*)(wp);
        *(float4*)wv[1]=*(const float4*)(wp+COUT);
        *(float4*)wv[2]=*(const float4*)(wp+2*COUT);
#pragma unroll
        for (int t=0;t<NPIX;t++){
          float v0=ok[t]?ip[t][0]:0.f;
          float v1=ok[t]?ip[t][1]:0.f;
          float v2=ok[t]?ip[t][2]:0.f;
#pragma unroll
          for (int j=0;j<4;j++)
            acc[t][j]=fmaf(v0,wv[0][j],fmaf(v1,wv[1][j],fmaf(v2,wv[2][j],acc[t][j])));
        }
      } else {
#pragma unroll 2
        for (int ci=0; ci<CLEN; ci+=4){
          float wv[4][4];
#pragma unroll
          for (int r=0;r<4;r++)
            *(float4*)wv[r] = *(const float4*)(wp + (ci+r)*COUT);
#pragma unroll
          for (int t=0;t<NPIX;t++){
            float va[4];
            *(float4*)va = ok[t] ? *(const float4*)(ip[t]+ci)
                                 : make_float4(0.f,0.f,0.f,0.f);
#pragma unroll
            for (int r=0;r<4;r++)
#pragma unroll
              for (int j=0;j<4;j++)
                acc[t][j]=fmaf(va[r],wv[r][j],acc[t][j]);
          }
        }
      }
    }
  }

  float bv[4]={0.f,0.f,0.f,0.f};
  if constexpr (BIAS) *(float4*)bv = *(const float4*)(bias+co);
#pragma unroll
  for (int t=0;t<NPIX;t++) if (pv[t]){
    float o[4];
#pragma unroll
    for (int j=0;j<4;j++){
      float v = acc[t][j]+bv[j];
      o[j] = ACT ? silu_f(v) : v;
    }
    *(float4*)(out + (size_t)(p0+t)*COUT + co) = *(float4*)o;
  }
}

// ---------------------------------------------------------------------------
// reduce G partials (stride n) + bias + optional silu, float4 per thread.
// ---------------------------------------------------------------------------
template<int G,int COUT,bool ACT>
__global__ __launch_bounds__(256) void reduce_k(
    const float* __restrict__ p, const float* __restrict__ bias,
    float* __restrict__ out, int n)
{
  int i = (blockIdx.x*256+threadIdx.x)*4;
  if (i>=n) return;
  float a[4]; *(float4*)a = *(const float4*)(p+i);
#pragma unroll
  for (int g=1; g<G; g++){
    float b[4]; *(float4*)b = *(const float4*)(p+(size_t)g*n+i);
#pragma unroll
    for (int j=0;j<4;j++) a[j]+=b[j];
  }
  float bv[4]; *(float4*)bv = *(const float4*)(bias + (i % COUT));
#pragma unroll
  for (int j=0;j<4;j++){
    float v=a[j]+bv[j];
    a[j] = ACT ? silu_f(v) : v;
  }
  *(float4*)(out+i) = *(float4*)a;
}

// ---------------------------------------------------------------------------
// conv_transpose 5x5 stride 2 SAME. All 4 output parities in one launch
// (parity = blockIdx.x & 3). iy = yy+j-1, ky = 2j+(py?0:1)  (verified r0).
// ---------------------------------------------------------------------------
template<int CIN,int COUT,int NPIX>
__global__ __launch_bounds__(256) void tconv_k(
    const float* __restrict__ in, const float* __restrict__ w,
    const float* __restrict__ bias, float* __restrict__ out,
    int N,int H,int W,int OH,int OW)
{
  constexpr int COQ = COUT/4;
  const int par = blockIdx.x & 3;
  const int py = par>>1, px = par&1;
  const int NKY = py?3:2, NKX = px?3:2;
  const int bx = blockIdx.x>>2;
  const int OHh=OH>>1, OWh=OW>>1;
  const int total = N*OHh*OWh;

  int idx = bx*256 + threadIdx.x;
  int cq = idx % COQ;
  int pg = idx / COQ;
  int co = cq*4;
  int p0 = pg*NPIX;
  if (p0 >= total) return;

  float acc[NPIX][4] = {};
  int yy[NPIX], xx[NPIX], nn[NPIX]; const float* base[NPIX]; bool pv[NPIX];
#pragma unroll
  for (int t=0;t<NPIX;t++){
    int p=p0+t; pv[t]=(p<total); int pp=pv[t]?p:p0;
    xx[t]=pp%OWh; int r=pp/OWh; yy[t]=r%OHh; nn[t]=r/OHh;
    base[t]=in+(size_t)nn[t]*H*W*CIN;
  }

  for (int j=0;j<NKY;j++){
    int ky = 2*j + (py?0:1);
    for (int i=0;i<NKX;i++){
      int kx = 2*i + (px?0:1);
      const float* wp = w + (size_t)((ky*5+kx)*CIN)*COUT + co;
      const float* ip[NPIX]; bool ok[NPIX];
#pragma unroll
      for (int t=0;t<NPIX;t++){
        int iy=yy[t]+j-1, ix=xx[t]+i-1;
        ok[t]=pv[t] && iy>=0 && iy<H && ix>=0 && ix<W;
        ip[t]=base[t]+(size_t)(iy*W+ix)*CIN;
      }
#pragma unroll 2
      for (int ci=0; ci<CIN; ci+=4){
        float wv[4][4];
#pragma unroll
        for (int r=0;r<4;r++)
          *(float4*)wv[r] = *(const float4*)(wp + (ci+r)*COUT);
#pragma unroll
        for (int t=0;t<NPIX;t++){
          float va[4];
          *(float4*)va = ok[t] ? *(const float4*)(ip[t]+ci)
                               : make_float4(0.f,0.f,0.f,0.f);
#pragma unroll
          for (int r=0;r<4;r++)
#pragma unroll
            for (int jj=0;jj<4;jj++)
              acc[t][jj]=fmaf(va[r],wv[r][jj],acc[t][jj]);
        }
      }
    }
  }

  float bv[4]; *(float4*)bv = *(const float4*)(bias+co);
#pragma unroll
  for (int t=0;t<NPIX;t++) if (pv[t]){
    float o[4];
#pragma unroll
    for (int jj=0;jj<4;jj++) o[jj]=silu_f(acc[t][jj]+bv[jj]);
    *(float4*)(out + (((size_t)nn[t]*OH + (2*yy[t]+py))*OW + (2*xx[t]+px))*COUT + co) = *(float4*)o;
  }
}

// ---------------------------------------------------------------------------
// VQ fused with conv3c partial reduction (2 partials, stride NLat*128) + bias.
// One wave per latent; 4 codes/lane; shuffle argmin, low-index tie-break.
// ---------------------------------------------------------------------------
__global__ __launch_bounds__(256) void vq_k(
    const float* __restrict__ p, const float* __restrict__ bias,
    const float* __restrict__ cb, float* __restrict__ q, int NLat)
{
  __shared__ float slat[4][128];
  int wave = threadIdx.x >> 6;
  int lane = threadIdx.x & 63;
  int l = blockIdx.x*4 + wave;
  if (l >= NLat) return;
  const float* p0 = p + (size_t)l*128;
  const float* p1 = p0 + (size_t)NLat*128;
  slat[wave][lane]    = p0[lane]    + p1[lane]    + bias[lane];
  slat[wave][lane+64] = p0[lane+64] + p1[lane+64] + bias[lane+64];

  float bestd = INFINITY; int besti = 0;
  for (int c0=0;c0<256;c0+=64){
    int c = c0 + lane;
    const float* cp = cb + (size_t)c*128;
    float d = 0.f;
#pragma unroll 8
    for (int k=0;k<128;k+=4){
      float4 cv = *reinterpret_cast<const float4*>(cp+k);
      float d0 = slat[wave][k+0]-cv.x;
      float d1 = slat[wave][k+1]-cv.y;
      float d2 = slat[wave][k+2]-cv.z;
      float d3 = slat[wave][k+3]-cv.w;
      d += d0*d0; d += d1*d1; d += d2*d2; d += d3*d3;
    }
    if (d < bestd) { bestd = d; besti = c; }
  }
  for (int off=32; off; off>>=1){
    float od = __shfl_down(bestd, off);
    int   oi = __shfl_down(besti, off);
    if (od < bestd || (od == bestd && oi < besti)) { bestd=od; besti=oi; }
  }
  besti = __shfl(besti, 0);
  const float* cp = cb + (size_t)besti*128;
  float* qp = q + (size_t)l*128;
  qp[lane]    = cp[lane];
  qp[lane+64] = cp[lane+64];
}

// ---------------------------------------------------------------------------
// Final 3x3 conv 32->3, thread = pixel, float4 in/w loads.
// ---------------------------------------------------------------------------
__global__ __launch_bounds__(256) void conv_last_k(
    const float* __restrict__ in, const float* __restrict__ w,
    const float* __restrict__ bias, float* __restrict__ out,
    int N,int H,int W)
{
  int p = blockIdx.x*256 + threadIdx.x;
  int total = N*H*W;
  if (p>=total) return;
  int x = p % W; int r = p / W; int y = r % H; int n = r / H;
  float a0=bias[0], a1=bias[1], a2=bias[2];
  const float* base = in + (size_t)n*H*W*32;
  for (int ky=0;ky<3;ky++){ int iy=y+ky-1; if(iy<0||iy>=H) continue;
    for (int kx=0;kx<3;kx++){ int ix=x+kx-1; if(ix<0||ix>=W) continue;
      const float* ip = base + (size_t)(iy*W+ix)*32;
      const float* wp = w + (size_t)((ky*3+kx)*32)*3;
#pragma unroll
      for (int ci=0;ci<32;ci+=4){
        float va[4]; *(float4*)va = *(const float4*)(ip+ci);
        float wv[12];
        *(float4*)(wv+0) = *(const float4*)(wp+ci*3+0);
        *(float4*)(wv+4) = *(const float4*)(wp+ci*3+4);
        *(float4*)(wv+8) = *(const float4*)(wp+ci*3+8);
#pragma unroll
        for (int r2=0;r2<4;r2++){
          a0 = fmaf(va[r2], wv[r2*3+0], a0);
          a1 = fmaf(va[r2], wv[r2*3+1], a1);
          a2 = fmaf(va[r2], wv[r2*3+2], a2);
        }
      }
    }
  }
  out[(size_t)p*3+0]=a0; out[(size_t)p*3+1]=a1; out[(size_t)p*3+2]=a2;
}

extern "C" void kernel_launch(void* const* d_in, const int* in_sizes, int n_in,
                              void* d_out, int out_size, void* d_ws, size_t ws_size,
                              hipStream_t stream) {
  const float* x    = (const float*)d_in[0];
  const float* k1   = (const float*)d_in[1];  const float* b1  = (const float*)d_in[2];
  const float* k1c  = (const float*)d_in[3];  const float* b1c = (const float*)d_in[4];
  const float* k2   = (const float*)d_in[5];  const float* b2  = (const float*)d_in[6];
  const float* k2c  = (const float*)d_in[7];  const float* b2c = (const float*)d_in[8];
  const float* k3   = (const float*)d_in[9];  const float* b3  = (const float*)d_in[10];
  const float* k3c  = (const float*)d_in[11]; const float* b3c = (const float*)d_in[12];
  const float* cb   = (const float*)d_in[13];
  const float* tk1  = (const float*)d_in[14]; const float* tb1  = (const float*)d_in[15];
  const float* tk1c = (const float*)d_in[16]; const float* tb1c = (const float*)d_in[17];
  const float* tk2  = (const float*)d_in[18]; const float* tb2  = (const float*)d_in[19];
  const float* tk2c = (const float*)d_in[20]; const float* tb2c = (const float*)d_in[21];
  const float* tk3  = (const float*)d_in[22]; const float* tb3  = (const float*)d_in[23];
  const float* tk3c = (const float*)d_in[24]; const float* tb3c = (const float*)d_in[25];
  float* out = (float*)d_out;

  float* A = (float*)d_ws;          // 1,048,576 floats (4 MB)
  float* B = A + 1048576;           // 4,194,304 floats (16 MB)

  dim3 blk(256);
  // encoder
  conv_k<11,11,2,4,  3, 32,2,true ,true ,1><<< 512, blk,0,stream>>>(x, k1, b1, A, 8,128,128,64,64);
  conv_k< 3, 3,1,1, 32, 32,2,true ,true ,1><<< 512, blk,0,stream>>>(A, k1c,b1c,B, 8, 64, 64,64,64);
  conv_k<11,11,2,4, 32, 64,2,false,false,2><<< 512, blk,0,stream>>>(B, k2, b2, A, 8, 64, 64,32,32);
  reduce_k<2, 64,true><<<512, blk,0,stream>>>(A, b2, B+1048576, 524288);
  conv_k< 3, 3,1,1, 64, 64,1,true ,true ,1><<< 512, blk,0,stream>>>(B+1048576, k2c,b2c,A, 8,32,32,32,32);
  conv_k<11,11,2,4, 64,128,2,false,false,4><<< 512, blk,0,stream>>>(A, k3, b3, B, 8, 32, 32,16,16);
  reduce_k<4,128,true><<<256, blk,0,stream>>>(B, b3, A+524288, 262144);
  conv_k< 3, 3,1,1,128,128,1,false,false,2><<< 512, blk,0,stream>>>(A+524288, k3c,b3c,B, 8,16,16,16,16);
  // vector quantization: sum conv3c partials + bias, argmin, gather
  vq_k<<<512, blk,0,stream>>>(B, b3c, cb, A, 2048);
  // decoder
  tconv_k<128,64,1><<< 512, blk,0,stream>>>(A,        tk1, tb1, B, 8,16,16,32,32);
  conv_k<3,3,1,1,64,64,1,true,true,1><<<512, blk,0,stream>>>(B, tk1c,tb1c, A+262144, 8,32,32,32,32);
  tconv_k< 64,32,2><<< 512, blk,0,stream>>>(A+262144, tk2, tb2, B, 8,32,32,64,64);
  conv_k<3,3,1,1,32,32,2,true,true,1><<<512, blk,0,stream>>>(B, tk2c,tb2c, A, 8,64,64,64,64);
  tconv_k< 32,32,2><<<2048, blk,0,stream>>>(A,        tk3, tb3, B, 8,64,64,128,128);
  conv_last_k<<<512, blk,0,stream>>>(B, tk3c, tb3c, out, 8,128,128);
}